// Round 10
// baseline (165.530 us; speedup 1.0000x reference)
//
#include <hip/hip_runtime.h>
#include <hip/hip_bf16.h>
#include <cstdint>

typedef unsigned short u16;
typedef __bf16 bf16_t;
typedef __bf16 bf16x8 __attribute__((ext_vector_type(8)));
typedef float f32x4 __attribute__((ext_vector_type(4)));

#define DM   512
#define DFF  2048
#define NEXP 8

__device__ __forceinline__ u16 f2bf(float f) {
  bf16_t b = (bf16_t)f;
  return __builtin_bit_cast(u16, b);
}
__device__ __forceinline__ uint32_t pack_bf2(float lo, float hi) {
  return (uint32_t)f2bf(lo) | ((uint32_t)f2bf(hi) << 16);
}
__device__ __forceinline__ float gelu_tanh(float x) {
  float x3 = x * x * x;
  float z = 0.7978845608028654f * (x + 0.044715f * x3);
  float az = fabsf(z);
  float e = __expf(2.0f * az);
  float t = 1.0f - 2.0f / (e + 1.0f);
  t = copysignf(t, z);
  return 0.5f * x * (1.0f + t);
}
__device__ __forceinline__ void async16(const u16* g, u16* l) {
  __builtin_amdgcn_global_load_lds((const __attribute__((address_space(1))) void*)g,
                                   (__attribute__((address_space(3))) void*)l, 16, 0, 0);
}

// ---------- transpose tile body: src [R][C] f32 (+e offset) -> dst [C][R] bf16
__device__ __forceinline__ void transpose_tile(const float* __restrict__ s,
                                               u16* __restrict__ d, int R, int C,
                                               int tileIdx) {
  __shared__ u16 tile[64][66];
  int tilesC = C >> 6;
  int bR = (tileIdx / tilesC) << 6;
  int bC = (tileIdx % tilesC) << 6;
  int rr = threadIdx.x >> 4;
  int cc = (threadIdx.x & 15) << 2;
#pragma unroll
  for (int i = 0; i < 4; ++i) {
    int r = (i << 4) + rr;
    float4 v = *(const float4*)(s + (size_t)(bR + r) * C + bC + cc);
    *(uint32_t*)&tile[r][cc]     = pack_bf2(v.x, v.y);
    *(uint32_t*)&tile[r][cc + 2] = pack_bf2(v.z, v.w);
  }
  __syncthreads();
  int c0 = threadIdx.x >> 5;
  int j  = (threadIdx.x & 31) << 1;
#pragma unroll
  for (int i = 0; i < 8; ++i) {
    int c = (i << 3) + c0;
    uint32_t v = (uint32_t)tile[j][c] | ((uint32_t)tile[j + 1][c] << 16);
    *(uint32_t*)(&d[(size_t)(bC + c) * R + bR + j]) = v;
  }
}

// ---------- fused prep: W1 transpose | W2 transpose | router
__global__ void k_prep(const float* __restrict__ W1, u16* __restrict__ W1T,
                       const float* __restrict__ W2, u16* __restrict__ W2T,
                       const float* __restrict__ x, const float* __restrict__ Wr,
                       const float* __restrict__ br, int* __restrict__ sel_idx,
                       float* __restrict__ sel_w, int Ntok) {
  int b = blockIdx.x;
  if (b < 2048) {
    int e = b >> 8, t = b & 255;
    transpose_tile(W1 + (size_t)e * DM * DFF, W1T + (size_t)e * DM * DFF, DM, DFF, t);
    return;
  }
  if (b < 4096) {
    int e = (b - 2048) >> 8, t = (b - 2048) & 255;
    transpose_tile(W2 + (size_t)e * DFF * DM, W2T + (size_t)e * DFF * DM, DFF, DM, t);
    return;
  }
  int rb = b - 4096;
  int wid = threadIdx.x >> 6;
  int lane = threadIdx.x & 63;
  int tok = (rb << 2) + wid;
  if (tok >= Ntok) return;
  const float4* xr = (const float4*)(x + (size_t)tok * DM);
  float4 x0 = xr[lane * 2], x1 = xr[lane * 2 + 1];
  float logit[NEXP];
#pragma unroll
  for (int e = 0; e < NEXP; ++e) {
    const float4* wr = (const float4*)(Wr + e * DM);
    float4 w0 = wr[lane * 2], w1 = wr[lane * 2 + 1];
    float p = x0.x * w0.x + x0.y * w0.y + x0.z * w0.z + x0.w * w0.w
            + x1.x * w1.x + x1.y * w1.y + x1.z * w1.z + x1.w * w1.w;
#pragma unroll
    for (int off = 32; off; off >>= 1) p += __shfl_xor(p, off, 64);
    logit[e] = p + br[e];
  }
  if (lane == 0) {
    float mx = logit[0];
#pragma unroll
    for (int e = 1; e < NEXP; ++e) mx = fmaxf(mx, logit[e]);
    float pr[NEXP];
#pragma unroll
    for (int e = 0; e < NEXP; ++e) pr[e] = __expf(logit[e] - mx);
    int i0 = 0;
#pragma unroll
    for (int e = 1; e < NEXP; ++e) if (pr[e] > pr[i0]) i0 = e;
    int i1 = -1;
#pragma unroll
    for (int e = 0; e < NEXP; ++e) {
      if (e == i0) continue;
      if (i1 < 0 || pr[e] > pr[i1]) i1 = e;
    }
    float s2 = pr[i0] + pr[i1];
    sel_idx[tok * 2]     = i0;
    sel_idx[tok * 2 + 1] = i1;
    sel_w[tok * 2]       = pr[i0] / s2;
    sel_w[tok * 2 + 1]   = pr[i1] / s2;
  }
}

// ---------- scatter (1 block, ballot-based), 128-row tile granularity
__global__ void k_scatter(const int* __restrict__ sel_idx, const float* __restrict__ sel_w,
                          int npairs, int* __restrict__ row_token, float* __restrict__ row_w,
                          int* __restrict__ pos_of, int* __restrict__ tileMeta,
                          int* __restrict__ gMeta) {
  __shared__ int cnt[NEXP], offs[NEXP], cur[NEXP];
  int tid = threadIdx.x;
  int lane = tid & 63;
  if (tid < NEXP) { cnt[tid] = 0; cur[tid] = 0; }
  __syncthreads();
  for (int p = tid; p < npairs; p += blockDim.x) {
    int e = sel_idx[p];
#pragma unroll
    for (int ex = 0; ex < NEXP; ++ex) {
      unsigned long long m = __ballot(e == ex);
      if (lane == 0 && m) atomicAdd(&cnt[ex], __popcll(m));
    }
  }
  __syncthreads();
  if (tid == 0) {
    int o = 0, nmt = 0;
    for (int e = 0; e < NEXP; ++e) {
      offs[e] = o;
      int c = cnt[e];
      int nt = (c + 127) >> 7;
      for (int t = 0; t < nt; ++t) {
        tileMeta[nmt * 3 + 0] = o + t * 128;
        tileMeta[nmt * 3 + 1] = o + c;
        tileMeta[nmt * 3 + 2] = e;
        ++nmt;
      }
      o += c;
    }
    gMeta[0] = nmt;
  }
  __syncthreads();
  for (int p = tid; p < npairs; p += blockDim.x) {
    int e = sel_idx[p];
    int pos = 0;
#pragma unroll
    for (int ex = 0; ex < NEXP; ++ex) {
      unsigned long long m = __ballot(e == ex);
      if (m) {
        int leader = __ffsll((long long)m) - 1;
        int base = 0;
        if (lane == leader) base = atomicAdd(&cur[ex], __popcll(m));
        base = __shfl(base, leader, 64);
        if (e == ex)
          pos = offs[ex] + base + __popcll(m & ((1ull << lane) - 1ull));
      }
    }
    row_token[pos] = p >> 1;
    row_w[pos] = sel_w[p];
    pos_of[p] = pos;
  }
}

// ---------- gather selected token rows -> bf16
__global__ void k_gather(const float* __restrict__ x, const int* __restrict__ row_token,
                         u16* __restrict__ Xg, int npairs) {
  int pos = (blockIdx.x << 2) + (threadIdx.x >> 6);
  int lane = threadIdx.x & 63;
  if (pos >= npairs) return;
  int tok = row_token[pos];
  const float4* src = (const float4*)(x + (size_t)tok * DM);
  float4 a = src[lane * 2], b = src[lane * 2 + 1];
  uint4 o;
  o.x = pack_bf2(a.x, a.y);
  o.y = pack_bf2(a.z, a.w);
  o.z = pack_bf2(b.x, b.y);
  o.w = pack_bf2(b.z, b.w);
  ((uint4*)(Xg + (size_t)pos * DM))[lane] = o;
}

// ---------- 128x128 grouped GEMM, BK=32, 2-slot ring (32KB -> 5 blocks/CU),
// lead-1 prefetch, 1 barrier/K-tile, 256 thr / 4 waves (2x2).
// Occupancy law (R4/R8/R9): GEMM time ~ 150us / blocks-per-CU -> maximize residency.
// Out: bf16 [NSPLIT][npairs][NFULL] (split stride pstride u16 elems)
template <int NFULL, int KTOT, int NSPLIT, bool GELU, bool SCALE>
__launch_bounds__(256)
__global__ void k_gemm(const u16* __restrict__ A, const u16* __restrict__ BT,
                       const float* __restrict__ bias, const float* __restrict__ row_w,
                       u16* __restrict__ Out, size_t pstride,
                       const int* __restrict__ tileMeta, const int* __restrict__ gMeta,
                       int maxmt) {
  constexpr int NTN = NFULL / 128;
  constexpr int SN  = (NTN >= 8) ? 8 : NTN;   // super width (nt)
  constexpr int NSN = NTN / SN;
  constexpr int SUPER = 8 * SN;               // blocks per super (8 mt x SN nt)
  constexpr int KCH = KTOT / NSPLIT;
  constexpr int NK  = KCH / 32;

  // 2 slots x (A 128x64B = 8KB @0, B 8KB @+4096 u16) = 32KB total
  __shared__ __align__(16) u16 smem[16384];

  int NB = gridDim.x;
  int bid = blockIdx.x;
  int wg = ((NB & 7) == 0) ? ((bid & 7) * (NB >> 3) + (bid >> 3)) : bid;  // XCD chunking
  int s = wg / SUPER, l = wg % SUPER;
  int nsm = maxmt >> 3;
  int split = s / (nsm * NSN);
  int srem  = s % (nsm * NSN);
  int sm = srem / NSN, sn = srem % NSN;
  int mt = sm * 8 + l / SN;
  int nt = sn * SN + l % SN;
  if (mt >= gMeta[0]) return;
  int posStart = tileMeta[mt * 3 + 0];
  int segEnd   = tileMeta[mt * 3 + 1];
  int e        = tileMeta[mt * 3 + 2];

  int tid = threadIdx.x, lane = tid & 63, wid = tid >> 6;
  int wm = wid >> 1, wn = wid & 1;             // 2 x 2 waves; wave tile 64 x 64

  const u16* Ab = A + (size_t)split * KCH;
  const u16* Bb = BT + ((size_t)e * NFULL + (size_t)nt * 128) * KTOT + (size_t)split * KCH;

  // staging: instr i covers rows i*64 + wid*16 + (lane>>2); chunk lane&3 of 64B row.
  // pre-swizzled source chunk = c ^ ((row>>1)&3)  (conflict-free on read, R8-verified)
  int l4 = lane >> 2, c4 = lane & 3;
  const u16* aS[2];
  const u16* bS[2];
#pragma unroll
  for (int i = 0; i < 2; ++i) {
    int r = i * 64 + wid * 16 + l4;
    int g = posStart + r; if (g >= segEnd) g = segEnd - 1;
    int cs = c4 ^ ((r >> 1) & 3);
    aS[i] = Ab + (size_t)g * KTOT + cs * 8;
    bS[i] = Bb + (size_t)r * KTOT + cs * 8;
  }

  auto stage = [&](int kt, int slot) {
    u16* as = smem + slot * 8192;
    u16* bs = as + 4096;
#pragma unroll
    for (int i = 0; i < 2; ++i) {
      async16(aS[i] + kt * 32, as + i * 2048 + wid * 512);
      async16(bS[i] + kt * 32, bs + i * 2048 + wid * 512);
    }
  };

  f32x4 acc[4][4] = {};

  stage(0, 0);
  asm volatile("s_waitcnt vmcnt(0)" ::: "memory");
  __builtin_amdgcn_s_barrier();
  asm volatile("" ::: "memory");

#pragma unroll 1
  for (int t = 0; t < NK; ++t) {
    // prefetch next tile into the other slot (its old contents barrier-sealed)
    if (t + 1 < NK) stage(t + 1, (t + 1) & 1);
    const char* AsB = (const char*)(smem + (t & 1) * 8192);
    const char* BsB = AsB + 8192;
    int kb = (lane >> 4) << 4;
    bf16x8 av[4], bv[4];
#pragma unroll
    for (int mi = 0; mi < 4; ++mi) {
      int row = (wm << 6) + (mi << 4) + (lane & 15);
      av[mi] = *(const bf16x8*)(AsB + row * 64 + (kb ^ (((row >> 1) & 3) << 4)));
    }
#pragma unroll
    for (int ni = 0; ni < 4; ++ni) {
      int row = (wn << 6) + (ni << 4) + (lane & 15);
      bv[ni] = *(const bf16x8*)(BsB + row * 64 + (kb ^ (((row >> 1) & 3) << 4)));
    }
    __builtin_amdgcn_s_setprio(1);
#pragma unroll
    for (int mi = 0; mi < 4; ++mi)
#pragma unroll
      for (int ni = 0; ni < 4; ++ni)
        acc[mi][ni] = __builtin_amdgcn_mfma_f32_16x16x32_bf16(av[mi], bv[ni], acc[mi][ni], 0, 0, 0);
    __builtin_amdgcn_s_setprio(0);
    if (t + 1 < NK) asm volatile("s_waitcnt vmcnt(0)" ::: "memory");  // next tile landed
    __builtin_amdgcn_s_barrier();
    asm volatile("" ::: "memory");
  }

  // ---------- epilogue: two 64-row chunks through LDS (Cs 64x136 u16 = 17.4KB <= 32KB)
  u16* Cs = smem;
  const float* biasE = bias + (size_t)e * NFULL;
  u16* OutS = Out + (size_t)split * pstride;
  int laneCol = lane & 15;
  int laneRow4 = (lane >> 4) << 2;
#pragma unroll
  for (int ch = 0; ch < 2; ++ch) {
    __syncthreads();   // seals K-loop reads (ch=0) / previous chunk's stores (ch=1)
    if (wm == ch) {
#pragma unroll
      for (int mi = 0; mi < 4; ++mi) {
#pragma unroll
        for (int j = 0; j < 4; ++j) {
          int rl = (mi << 4) + laneRow4 + j;      // 0..63 within chunk
          int m = posStart + (ch << 6) + rl;
          int mc = m < segEnd ? m : segEnd - 1;
          float w = 1.0f;
          if constexpr (SCALE) w = row_w[mc];
#pragma unroll
          for (int ni = 0; ni < 4; ++ni) {
            int cl = (wn << 6) + (ni << 4) + laneCol;
            float v = acc[mi][ni][j];
            if (split == 0) v += biasE[nt * 128 + cl];
            if constexpr (GELU) v = gelu_tanh(v);
            if constexpr (SCALE) v *= w;
            Cs[rl * 136 + cl] = f2bf(v);
          }
        }
      }
    }
    __syncthreads();
    int r0 = tid >> 4, q = tid & 15;              // 16 rows/pass, 4 passes
#pragma unroll
    for (int i = 0; i < 4; ++i) {
      int rl = (i << 4) + r0;
      int m = posStart + (ch << 6) + rl;
      if (m < segEnd)
        *((uint4*)(OutS + (size_t)m * NFULL + (nt << 7)) + q) =
            ((uint4*)(Cs + (size_t)rl * 136))[q];
    }
  }
}

// ---------- combine: out[tok] = sum over splits x {pos0,pos1} of bf16 partials
template <int NSPLIT>
__global__ void k_combine(const u16* __restrict__ P, size_t pstride,
                          const int* __restrict__ pos_of, float* __restrict__ out, int Ntok) {
  int tok = (blockIdx.x << 2) + (threadIdx.x >> 6);
  int lane = threadIdx.x & 63;
  if (tok >= Ntok) return;
  int p0 = pos_of[tok * 2], p1 = pos_of[tok * 2 + 1];
  float s[8] = {};
#pragma unroll
  for (int sp = 0; sp < NSPLIT; ++sp) {
    bf16x8 a = ((const bf16x8*)(P + sp * pstride + (size_t)p0 * DM))[lane];
    bf16x8 b = ((const bf16x8*)(P + sp * pstride + (size_t)p1 * DM))[lane];
#pragma unroll
    for (int i = 0; i < 8; ++i) s[i] += (float)a[i] + (float)b[i];
  }
  float4* o = (float4*)(out + (size_t)tok * DM + lane * 8);
  o[0] = make_float4(s[0], s[1], s[2], s[3]);
  o[1] = make_float4(s[4], s[5], s[6], s[7]);
}

extern "C" void kernel_launch(void* const* d_in, const int* in_sizes, int n_in,
                              void* d_out, int out_size, void* d_ws, size_t ws_size,
                              hipStream_t stream) {
  const float* x  = (const float*)d_in[0];
  const float* Wr = (const float*)d_in[1];
  const float* br = (const float*)d_in[2];
  const float* W1 = (const float*)d_in[3];
  const float* b1 = (const float*)d_in[4];
  const float* W2 = (const float*)d_in[5];
  const float* b2 = (const float*)d_in[6];
  float* out = (float*)d_out;

  int Ntok = in_sizes[0] / DM;          // 4096
  int npairs = Ntok * 2;                // 8192
  int maxmt = npairs / 128 + NEXP;      // 72 (multiple of 8)
  size_t pstride = (size_t)npairs * DM; // u16 elems per split

  char* p = (char*)d_ws;
  u16* W1T = (u16*)p;  p += (size_t)NEXP * DFF * DM * 2;
  u16* W2T = (u16*)p;  p += (size_t)NEXP * DM * DFF * 2;
  u16* Xg  = (u16*)p;  p += (size_t)npairs * DM * 2;
  u16* H   = (u16*)p;  p += (size_t)npairs * DFF * 2;
  u16* Part = (u16*)p; p += 2 * pstride * 2;          // [2][npairs][DM] bf16
  int* sel_idx   = (int*)p;   p += (size_t)npairs * 4;
  float* sel_w   = (float*)p; p += (size_t)npairs * 4;
  int* pos_of    = (int*)p;   p += (size_t)npairs * 4;
  int* row_token = (int*)p;   p += (size_t)npairs * 4;
  float* row_w   = (float*)p; p += (size_t)npairs * 4;
  int* tileMeta  = (int*)p;   p += (size_t)(maxmt * 3 + 16) * 4;
  int* gMeta     = (int*)p;   p += 64;

  k_prep<<<dim3(4096 + Ntok / 4), 256, 0, stream>>>(W1, W1T, W2, W2T, x, Wr, br,
                                                    sel_idx, sel_w, Ntok);
  k_scatter<<<dim3(1), 1024, 0, stream>>>(sel_idx, sel_w, npairs, row_token, row_w,
                                          pos_of, tileMeta, gMeta);
  k_gather<<<dim3(npairs / 4), 256, 0, stream>>>(x, row_token, Xg, npairs);
  // GEMM1: H = gelu(Xg * W1T + b1), 128x128, grid 72*16 = 1152
  k_gemm<DFF, DM, 1, true, false>
      <<<dim3(maxmt * (DFF / 128)), 256, 0, stream>>>(
          Xg, W1T, b1, nullptr, H, 0, tileMeta, gMeta, maxmt);
  // GEMM2: Part[s] = (H_s * W2T_s + (s==0)*b2) * row_w, split-K=2, grid 72*4*2 = 576
  k_gemm<DM, DFF, 2, false, true>
      <<<dim3(maxmt * (DM / 128) * 2), 256, 0, stream>>>(
          H, W2T, b2, row_w, Part, pstride, tileMeta, gMeta, maxmt);
  k_combine<2><<<dim3(Ntok / 4), 256, 0, stream>>>(Part, pstride, pos_of, out, Ntok);
}